// Round 5
// baseline (175.906 us; speedup 1.0000x reference)
//
#include <hip/hip_runtime.h>

#define EPS 1e-5f

typedef _Float16 f16x8 __attribute__((ext_vector_type(8)));
typedef _Float16 f16x4 __attribute__((ext_vector_type(4)));
typedef float f32x4 __attribute__((ext_vector_type(4)));

// ---- workspace layout (float offsets) ----
#define XT_OFF    0u          // 256*1024 fp32
#define ACT1_OFF  262144u     // f16 196*1024*16
#define ACT2_OFF  1867776u    // f16 144*1024*32
#define ACT3_OFF  4227072u    // f16 100*1024*64
#define W2H_OFF   7503872u    // f16 144*10*512 = 737,280 halves  [p][pos10][o32][c16], pos9 zero
#define W3H_OFF   7872512u    // f16 900*2048  = 1,843,200 halves [p*9+pos][o64][c32]
#define FP_OFF    9598976u    // fp32 100*10*1024
#define ACC_OFF   10622976u   // fp32 224: s1(16) q1(16) s2(32) q2(32) s3(64) q3(64)

// ---------------- prep: coalesced LDS-tiled transposes + acc zero ----------------
__global__ __launch_bounds__(256) void k_prep(const float* __restrict__ W2,
                                              const float* __restrict__ W3,
                                              const float* __restrict__ x,
                                              _Float16* __restrict__ W2h,
                                              _Float16* __restrict__ W3h,
                                              float* __restrict__ xT,
                                              float* __restrict__ acc) {
    int gb = blockIdx.x, tid = threadIdx.x;
    __shared__ float tile[32][33];
    int tx = tid & 31, ty = tid >> 5;                 // 32 x 8
    if (gb < 656) {
        // ---- W2 transpose: tiles 16 (rows) x 41 (cols) ----
        int tR = gb / 41, tC = gb % 41;
        int oc0 = tR * 32, pp0 = tC * 32;
#pragma unroll
        for (int r = 0; r < 4; r++) {
            int col = pp0 + tx;
            if (col < 1296) tile[ty + 8 * r][tx] = W2[(size_t)(oc0 + ty + 8 * r) * 1296 + col];
        }
        __syncthreads();
#pragma unroll
        for (int r = 0; r < 4; r++) {
            int pr = pp0 + ty + 8 * r;
            if (pr < 1296) {
                int p = pr / 9, pos = pr - 9 * p;
                W2h[(size_t)(p * 10 + pos) * 512 + oc0 + tx] = (_Float16)tile[tx][ty + 8 * r];
            }
        }
        return;
    }
    if (gb < 692) {
        // ---- zero plane pos=9 of W2h (144*512 halves) + acc zero ----
        if (gb == 656 && tid < 224) acc[tid] = 0.f;
        int idx = (gb - 656) * 256 + tid;             // 0..9215
        int p = idx >> 6, ocv = idx & 63;
        f16x8 z = {(_Float16)0.f, (_Float16)0.f, (_Float16)0.f, (_Float16)0.f,
                   (_Float16)0.f, (_Float16)0.f, (_Float16)0.f, (_Float16)0.f};
        *(f16x8*)(W2h + (size_t)(p * 10 + 9) * 512 + ocv * 8) = z;
        return;
    }
    if (gb < 2548) {
        // ---- W3 transpose: tiles 64 (rows) x 29 (cols) ----
        int t = gb - 692;
        int tR = t / 29, tC = t % 29;
        int oc0 = tR * 32, pp0 = tC * 32;
#pragma unroll
        for (int r = 0; r < 4; r++) {
            int col = pp0 + tx;
            if (col < 900) tile[ty + 8 * r][tx] = W3[(size_t)(oc0 + ty + 8 * r) * 900 + col];
        }
        __syncthreads();
#pragma unroll
        for (int r = 0; r < 4; r++) {
            int pr = pp0 + ty + 8 * r;
            if (pr < 900) W3h[(size_t)pr * 2048 + oc0 + tx] = (_Float16)tile[tx][ty + 8 * r];
        }
        return;
    }
    {
        // ---- x transpose: 1024 tiles of 16x16 ----
        int t = gb - 2548;
        float* t17 = &tile[0][0];                     // use as [16][17]
        int tx4 = tid & 15, ty4 = tid >> 4;
        int p0 = (t & 15) * 16, b0 = (t >> 4) * 16;
        t17[ty4 * 17 + tx4] = x[(b0 + ty4) * 256 + p0 + tx4];
        __syncthreads();
        xT[(p0 + ty4) * 1024 + b0 + tx4] = t17[tx4 * 17 + ty4];
    }
}

// ---------------- LC1 (fp32 math): xT -> act1h f16 [p][b][c16] RAW; block stats -> atomicAdd acc1 ----------------
// grid: 784 blocks 1-D, XCD-contiguous swizzle (784 = 8*98)
__global__ __launch_bounds__(256) void k_lc1(const float* __restrict__ xT,
                                             const float* __restrict__ W1,
                                             const float* __restrict__ b1,
                                             _Float16* __restrict__ act1h,
                                             float* __restrict__ acc1) {   // s[16] q[16]
    int bid = blockIdx.x;
    int wg = (bid & 7) * 98 + (bid >> 3);   // XCD j owns wg in [j*98, (j+1)*98)
    int p = wg >> 2;                        // 0..195, contiguous per XCD
    int i = p / 14, j = p % 14;
    int tid = threadIdx.x;
    int b = (wg & 3) * 256 + tid;
    __shared__ float wS[144], bS[16];
    __shared__ float red[256 * 33];  // [thread][32 vals], pad 33 -> conflict-free
    __shared__ float pp[4 * 33];
    if (tid < 144) { int o = tid / 9, k = tid % 9; wS[tid] = W1[(o * 196 + p) * 9 + k]; }
    if (tid < 16) bS[tid] = b1[tid * 196 + p];
    __syncthreads();
    float xv[9];
#pragma unroll
    for (int di = 0; di < 3; di++)
#pragma unroll
        for (int dj = 0; dj < 3; dj++)
            xv[di * 3 + dj] = xT[((i + di) * 16 + (j + dj)) * 1024 + b];
    float accv[16];
#pragma unroll
    for (int o = 0; o < 16; o++) {
        float acc = bS[o];
#pragma unroll
        for (int k = 0; k < 9; k++) acc += wS[o * 9 + k] * xv[k];
        accv[o] = acc;
    }
    f16x8 lo, hi;
#pragma unroll
    for (int e = 0; e < 8; e++) { lo[e] = (_Float16)accv[e]; hi[e] = (_Float16)accv[8 + e]; }
    _Float16* dst = act1h + ((size_t)(p * 1024 + b)) * 16;
    *(f16x8*)dst = lo;
    *(f16x8*)(dst + 8) = hi;
    // ---- block-level stat reduction (s rows 0..15, q rows 16..31) ----
#pragma unroll
    for (int o = 0; o < 16; o++) {
        red[tid * 33 + o] = accv[o];
        red[tid * 33 + 16 + o] = accv[o] * accv[o];
    }
    __syncthreads();
    {
        int w = tid >> 6, lane = tid & 63, v = lane & 31, h = lane >> 5;
        int rbase = w * 64 + h * 32;
        float ssum = 0.f;
#pragma unroll
        for (int k = 0; k < 32; k++) ssum += red[(rbase + k) * 33 + v];
        ssum += __shfl_down(ssum, 32);
        if (h == 0) pp[w * 33 + v] = ssum;
    }
    __syncthreads();
    if (tid < 32) {
        float t4 = pp[tid] + pp[33 + tid] + pp[66 + tid] + pp[99 + tid];
        atomicAdd(acc1 + tid, t4);
    }
}

// ---------------- LC2 MFMA: act1h (+BN1/ReLU on read) -> act2h RAW; stats -> atomicAdd acc2 ----------------
// grid: 1152 blocks 1-D, XCD swizzle (1152 = 8*144 -> 18 contiguous p per XCD)
// 8 bgroups of 128, wave o32 x b32 (nt=2): 18 waves/CU for latency hiding
__global__ __launch_bounds__(256) void k_lc2m(const _Float16* __restrict__ act1h,
                                              const _Float16* __restrict__ W2h,
                                              const float* __restrict__ b2,
                                              const float* __restrict__ acc1,  // s[16] q[16]
                                              const float* __restrict__ g1,
                                              const float* __restrict__ be1,
                                              _Float16* __restrict__ act2h,
                                              float* __restrict__ acc2) {      // s[32] q[32]
    int bid = blockIdx.x;
    int wg = (bid & 7) * 144 + (bid >> 3);
    int p = wg >> 3, i = p / 12, j = p % 12;
    int tid = threadIdx.x, wv = tid >> 6, lane = tid & 63, n = lane & 15, quad = lane >> 4;
    int bbase = (wg & 7) * 128 + wv * 32;
    const float invN1 = 1.f / (1024.f * 196.f);
    f16x8 a8, c8;
#pragma unroll
    for (int e = 0; e < 8; e++) {
        int ch = (quad & 1) * 8 + e;
        float s = acc1[ch], q = acc1[16 + ch];
        float m = s * invN1, var = q * invN1 - m * m;
        float r = rsqrtf(var + EPS);
        float av = g1[ch] * r;
        a8[e] = (_Float16)av;
        c8[e] = (_Float16)(be1[ch] - m * av);
    }
    f32x4 acc[2][2] = {};
#pragma unroll
    for (int t = 0; t < 5; t++) {
        int posA = 2 * t + (quad >> 1);         // 0..9 ; 9 hits W2h zero plane
        int posB = posA > 8 ? 8 : posA;         // B reads pos8 (A slot is zero)
        int ip = (i + posB / 3) * 14 + (j + posB % 3);
        f16x8 afr[2];
#pragma unroll
        for (int ot = 0; ot < 2; ot++)
            afr[ot] = *(const f16x8*)(W2h + (size_t)(p * 10 + posA) * 512 + (ot * 16 + n) * 16 + (quad & 1) * 8);
#pragma unroll
        for (int nt = 0; nt < 2; nt++) {
            f16x8 xv = *(const f16x8*)(act1h + ((size_t)(ip * 1024 + bbase + nt * 16 + n)) * 16 + (quad & 1) * 8);
#pragma unroll
            for (int e = 0; e < 8; e++) {
                _Float16 v = xv[e] * a8[e] + c8[e];
                xv[e] = v > (_Float16)0.f ? v : (_Float16)0.f;
            }
#pragma unroll
            for (int ot = 0; ot < 2; ot++)
                acc[ot][nt] = __builtin_amdgcn_mfma_f32_16x16x32_f16(afr[ot], xv, acc[ot][nt], 0, 0, 0);
        }
    }
    float s_[8] = {}, q_[8] = {};
#pragma unroll
    for (int ot = 0; ot < 2; ot++) {
        float bias[4];
#pragma unroll
        for (int r = 0; r < 4; r++) bias[r] = b2[(ot * 16 + quad * 4 + r) * 144 + p];
#pragma unroll
        for (int nt = 0; nt < 2; nt++) {
            int b = bbase + nt * 16 + n;
            f16x4 st;
#pragma unroll
            for (int r = 0; r < 4; r++) {
                float v = acc[ot][nt][r] + bias[r];
                st[r] = (_Float16)v;
                s_[ot * 4 + r] += v; q_[ot * 4 + r] += v * v;
            }
            *(f16x4*)(act2h + ((size_t)(p * 1024 + b)) * 32 + ot * 16 + quad * 4) = st;
        }
    }
    __shared__ float red[64 * 65];
#pragma unroll
    for (int u = 0; u < 8; u++) {
        int o = (u >> 2) * 16 + quad * 4 + (u & 3);
        red[(2 * o) * 65 + wv * 16 + n] = s_[u];
        red[(2 * o + 1) * 65 + wv * 16 + n] = q_[u];
    }
    __syncthreads();
    if (tid < 64) {
        const float* row = red + tid * 65;
        float t0 = 0.f;
#pragma unroll
        for (int c = 0; c < 64; c++) t0 += row[c];
        atomicAdd(acc2 + (tid & 1) * 32 + (tid >> 1), t0);
    }
}

// ---------------- LC3 MFMA: act2h (+BN2/ReLU on read) -> act3h RAW; stats -> atomicAdd acc3 ----------------
// grid: 800 blocks 1-D, XCD swizzle (800 = 8*100 -> 12-13 contiguous p per XCD)
// 8 bgroups of 128, wave o64 x b32 (nt=2): 12.5 waves/CU
__global__ __launch_bounds__(256) void k_lc3m(const _Float16* __restrict__ act2h,
                                              const _Float16* __restrict__ W3h,
                                              const float* __restrict__ b3,
                                              const float* __restrict__ acc2,  // s[32] q[32]
                                              const float* __restrict__ g2,
                                              const float* __restrict__ be2,
                                              _Float16* __restrict__ act3h,
                                              float* __restrict__ acc3) {      // s[64] q[64]
    int bid = blockIdx.x;
    int wg = (bid & 7) * 100 + (bid >> 3);
    int p = wg >> 3, i = p / 10, j = p % 10;
    int tid = threadIdx.x, wv = tid >> 6, lane = tid & 63, n = lane & 15, quad = lane >> 4;
    int bbase = (wg & 7) * 128 + wv * 32;
    const float invN2 = 1.f / (1024.f * 144.f);
    f16x8 a8, c8;
#pragma unroll
    for (int e = 0; e < 8; e++) {
        int ch = quad * 8 + e;
        float s = acc2[ch], q = acc2[32 + ch];
        float m = s * invN2, var = q * invN2 - m * m;
        float r = rsqrtf(var + EPS);
        float av = g2[ch] * r;
        a8[e] = (_Float16)av;
        c8[e] = (_Float16)(be2[ch] - m * av);
    }
    f32x4 acc[4][2] = {};
#pragma unroll
    for (int pos = 0; pos < 9; pos++) {
        int ip = (i + pos / 3) * 12 + (j + pos % 3);
        f16x8 afr[4];
#pragma unroll
        for (int ot = 0; ot < 4; ot++)
            afr[ot] = *(const f16x8*)(W3h + (size_t)(p * 9 + pos) * 2048 + (ot * 16 + n) * 32 + quad * 8);
#pragma unroll
        for (int nt = 0; nt < 2; nt++) {
            f16x8 xv = *(const f16x8*)(act2h + ((size_t)(ip * 1024 + bbase + nt * 16 + n)) * 32 + quad * 8);
#pragma unroll
            for (int e = 0; e < 8; e++) {
                _Float16 v = xv[e] * a8[e] + c8[e];
                xv[e] = v > (_Float16)0.f ? v : (_Float16)0.f;
            }
#pragma unroll
            for (int ot = 0; ot < 4; ot++)
                acc[ot][nt] = __builtin_amdgcn_mfma_f32_16x16x32_f16(afr[ot], xv, acc[ot][nt], 0, 0, 0);
        }
    }
    float s_[16] = {}, q_[16] = {};
#pragma unroll
    for (int ot = 0; ot < 4; ot++) {
        float bias[4];
#pragma unroll
        for (int r = 0; r < 4; r++) bias[r] = b3[(ot * 16 + quad * 4 + r) * 100 + p];
#pragma unroll
        for (int nt = 0; nt < 2; nt++) {
            int b = bbase + nt * 16 + n;
            f16x4 st;
#pragma unroll
            for (int r = 0; r < 4; r++) {
                float v = acc[ot][nt][r] + bias[r];
                st[r] = (_Float16)v;
                s_[ot * 4 + r] += v; q_[ot * 4 + r] += v * v;
            }
            *(f16x4*)(act3h + ((size_t)(p * 1024 + b)) * 64 + ot * 16 + quad * 4) = st;
        }
    }
    __shared__ float red[128 * 65];
#pragma unroll
    for (int u = 0; u < 16; u++) {
        int o = (u >> 2) * 16 + quad * 4 + (u & 3);
        red[(2 * o) * 65 + wv * 16 + n] = s_[u];
        red[(2 * o + 1) * 65 + wv * 16 + n] = q_[u];
    }
    __syncthreads();
    if (tid < 128) {
        const float* row = red + tid * 65;
        float t0 = 0.f;
#pragma unroll
        for (int c = 0; c < 64; c++) t0 += row[c];
        atomicAdd(acc3 + (tid & 1) * 64 + (tid >> 1), t0);
    }
}

// ---------------- FC: tanh(BN3(act3h)) @ fcW^T -> partials [p][jj][b] ----------------
__global__ __launch_bounds__(256) void k_fc(const _Float16* __restrict__ act3h,
                                            const float* __restrict__ fcW,
                                            const float* __restrict__ acc3,  // s[64] q[64]
                                            const float* __restrict__ g3,
                                            const float* __restrict__ be3,
                                            float* __restrict__ fpart) {
    int p = blockIdx.y;
    int tid = threadIdx.x;
    int b = blockIdx.x * 256 + tid;
    __shared__ float wS[640], aS[64], cS[64];
    for (int idx = tid; idx < 640; idx += 256) {
        int o = idx / 10, jj = idx % 10;
        wS[idx] = fcW[jj * 6400 + o * 100 + p];
    }
    if (tid < 64) {
        const float invN3 = 1.f / (1024.f * 100.f);
        float s = acc3[tid], q = acc3[64 + tid];
        float m = s * invN3, var = q * invN3 - m * m;
        float r = rsqrtf(var + EPS);
        float av = g3[tid] * r;
        aS[tid] = av; cS[tid] = be3[tid] - m * av;
    }
    __syncthreads();
    float acc[10];
#pragma unroll
    for (int jj = 0; jj < 10; jj++) acc[jj] = 0.f;
    const _Float16* src = act3h + ((size_t)(p * 1024 + b)) * 64;
    for (int o8 = 0; o8 < 8; o8++) {
        f16x8 xv = *(const f16x8*)(src + o8 * 8);
#pragma unroll
        for (int e = 0; e < 8; e++) {
            int o = o8 * 8 + e;
            float v = fmaf(aS[o], (float)xv[e], cS[o]);
            float e2 = __expf(2.f * v);
            v = 1.f - 2.f / (e2 + 1.f);   // tanh, safe at +/-inf
#pragma unroll
            for (int jj = 0; jj < 10; jj++) acc[jj] = fmaf(wS[o * 10 + jj], v, acc[jj]);
        }
    }
#pragma unroll
    for (int jj = 0; jj < 10; jj++) fpart[((size_t)p * 10 + jj) * 1024 + b] = acc[jj];
}

// ---------------- reduce fc partials + bias -> out ----------------
__global__ __launch_bounds__(256) void k_fc_reduce(const float* __restrict__ fpart,
                                                   const float* __restrict__ fcb,
                                                   float* __restrict__ out) {
    int idx = blockIdx.x * 256 + threadIdx.x;  // jj*1024 + b
    int jj = idx >> 10, b = idx & 1023;
    float acc = fcb[jj];
    for (int p = 0; p < 100; p++) acc += fpart[(p * 10 + jj) * 1024 + b];
    out[b * 10 + jj] = acc;
}

extern "C" void kernel_launch(void* const* d_in, const int* in_sizes, int n_in,
                              void* d_out, int out_size, void* d_ws, size_t ws_size,
                              hipStream_t stream) {
    const float* x   = (const float*)d_in[0];
    const float* W1  = (const float*)d_in[1];
    const float* b1  = (const float*)d_in[2];
    const float* g1  = (const float*)d_in[3];
    const float* be1 = (const float*)d_in[4];
    const float* W2  = (const float*)d_in[5];
    const float* b2  = (const float*)d_in[6];
    const float* g2  = (const float*)d_in[7];
    const float* be2 = (const float*)d_in[8];
    const float* W3  = (const float*)d_in[9];
    const float* b3  = (const float*)d_in[10];
    const float* g3  = (const float*)d_in[11];
    const float* be3 = (const float*)d_in[12];
    const float* fcW = (const float*)d_in[13];
    const float* fcb = (const float*)d_in[14];
    float* out = (float*)d_out;
    float* ws = (float*)d_ws;

    float* xT    = ws + XT_OFF;
    _Float16* act1h = (_Float16*)(ws + ACT1_OFF);
    _Float16* act2h = (_Float16*)(ws + ACT2_OFF);
    _Float16* act3h = (_Float16*)(ws + ACT3_OFF);
    _Float16* W2h   = (_Float16*)(ws + W2H_OFF);
    _Float16* W3h   = (_Float16*)(ws + W3H_OFF);
    float* fp   = ws + FP_OFF;
    float* acc  = ws + ACC_OFF;

    k_prep<<<3572, 256, 0, stream>>>(W2, W3, x, W2h, W3h, xT, acc);
    k_lc1<<<784, 256, 0, stream>>>(xT, W1, b1, act1h, acc);
    k_lc2m<<<1152, 256, 0, stream>>>(act1h, W2h, b2, acc, g1, be1, act2h, acc + 32);
    k_lc3m<<<800, 256, 0, stream>>>(act2h, W3h, b3, acc + 32, g2, be2, act3h, acc + 96);
    k_fc<<<dim3(4, 100), 256, 0, stream>>>(act3h, fcW, acc + 96, g3, be3, fp);
    k_fc_reduce<<<40, 256, 0, stream>>>(fp, fcb, out);
}

// Round 6
// 160.292 us; speedup vs baseline: 1.0974x; 1.0974x over previous
//
#include <hip/hip_runtime.h>

#define EPS 1e-5f

typedef _Float16 f16x8 __attribute__((ext_vector_type(8)));
typedef _Float16 f16x4 __attribute__((ext_vector_type(4)));
typedef float f32x4 __attribute__((ext_vector_type(4)));

// ---- workspace layout (float offsets) ----
#define XT_OFF    0u          // 256*1024 fp32
#define ACT1_OFF  262144u     // f16 196*1024*16
#define ACT2_OFF  1867776u    // f16 144*1024*32
#define ACT3_OFF  4227072u    // f16 100*1024*64
#define W2H_OFF   7503872u    // f16 144*10*512 = 737,280 halves  [p][pos10][o32][c16], pos9 zero
#define W3H_OFF   7872512u    // f16 900*2048  = 1,843,200 halves [p*9+pos][o64][c32]
#define FP_OFF    9598976u    // fp32 100*10*1024
#define ACC_OFF   10622976u   // fp32 224: s1(16) q1(16) s2(32) q2(32) s3(64) q3(64)

// ---------------- prep: coalesced LDS-tiled transposes + acc zero ----------------
__global__ __launch_bounds__(256) void k_prep(const float* __restrict__ W2,
                                              const float* __restrict__ W3,
                                              const float* __restrict__ x,
                                              _Float16* __restrict__ W2h,
                                              _Float16* __restrict__ W3h,
                                              float* __restrict__ xT,
                                              float* __restrict__ acc) {
    int gb = blockIdx.x, tid = threadIdx.x;
    __shared__ float tile[32][33];
    int tx = tid & 31, ty = tid >> 5;                 // 32 x 8
    if (gb < 656) {
        // ---- W2 transpose: tiles 16 (rows) x 41 (cols) ----
        int tR = gb / 41, tC = gb % 41;
        int oc0 = tR * 32, pp0 = tC * 32;
#pragma unroll
        for (int r = 0; r < 4; r++) {
            int col = pp0 + tx;
            if (col < 1296) tile[ty + 8 * r][tx] = W2[(size_t)(oc0 + ty + 8 * r) * 1296 + col];
        }
        __syncthreads();
#pragma unroll
        for (int r = 0; r < 4; r++) {
            int pr = pp0 + ty + 8 * r;
            if (pr < 1296) {
                int p = pr / 9, pos = pr - 9 * p;
                W2h[(size_t)(p * 10 + pos) * 512 + oc0 + tx] = (_Float16)tile[tx][ty + 8 * r];
            }
        }
        return;
    }
    if (gb < 692) {
        // ---- zero plane pos=9 of W2h (144*512 halves) + acc zero ----
        if (gb == 656 && tid < 224) acc[tid] = 0.f;
        int idx = (gb - 656) * 256 + tid;             // 0..9215
        int p = idx >> 6, ocv = idx & 63;
        f16x8 z = {(_Float16)0.f, (_Float16)0.f, (_Float16)0.f, (_Float16)0.f,
                   (_Float16)0.f, (_Float16)0.f, (_Float16)0.f, (_Float16)0.f};
        *(f16x8*)(W2h + (size_t)(p * 10 + 9) * 512 + ocv * 8) = z;
        return;
    }
    if (gb < 2548) {
        // ---- W3 transpose: tiles 64 (rows) x 29 (cols) ----
        int t = gb - 692;
        int tR = t / 29, tC = t % 29;
        int oc0 = tR * 32, pp0 = tC * 32;
#pragma unroll
        for (int r = 0; r < 4; r++) {
            int col = pp0 + tx;
            if (col < 900) tile[ty + 8 * r][tx] = W3[(size_t)(oc0 + ty + 8 * r) * 900 + col];
        }
        __syncthreads();
#pragma unroll
        for (int r = 0; r < 4; r++) {
            int pr = pp0 + ty + 8 * r;
            if (pr < 900) W3h[(size_t)pr * 2048 + oc0 + tx] = (_Float16)tile[tx][ty + 8 * r];
        }
        return;
    }
    {
        // ---- x transpose: 1024 tiles of 16x16 ----
        int t = gb - 2548;
        float* t17 = &tile[0][0];                     // use as [16][17]
        int tx4 = tid & 15, ty4 = tid >> 4;
        int p0 = (t & 15) * 16, b0 = (t >> 4) * 16;
        t17[ty4 * 17 + tx4] = x[(b0 + ty4) * 256 + p0 + tx4];
        __syncthreads();
        xT[(p0 + ty4) * 1024 + b0 + tx4] = t17[tx4 * 17 + ty4];
    }
}

// ---------------- LC1 (fp32 math): xT -> act1h f16 [p][b][c16] RAW; block stats -> atomicAdd acc1 ----------------
// grid: 784 blocks 1-D, XCD-contiguous swizzle (784 = 8*98)
__global__ __launch_bounds__(256) void k_lc1(const float* __restrict__ xT,
                                             const float* __restrict__ W1,
                                             const float* __restrict__ b1,
                                             _Float16* __restrict__ act1h,
                                             float* __restrict__ acc1) {   // s[16] q[16]
    int bid = blockIdx.x;
    int wg = (bid & 7) * 98 + (bid >> 3);   // XCD j owns wg in [j*98, (j+1)*98)
    int p = wg >> 2;                        // 0..195, contiguous per XCD
    int i = p / 14, j = p % 14;
    int tid = threadIdx.x;
    int b = (wg & 3) * 256 + tid;
    __shared__ float wS[144], bS[16];
    __shared__ float red[256 * 33];  // [thread][32 vals], pad 33 -> conflict-free
    __shared__ float pp[4 * 33];
    if (tid < 144) { int o = tid / 9, k = tid % 9; wS[tid] = W1[(o * 196 + p) * 9 + k]; }
    if (tid < 16) bS[tid] = b1[tid * 196 + p];
    __syncthreads();
    float xv[9];
#pragma unroll
    for (int di = 0; di < 3; di++)
#pragma unroll
        for (int dj = 0; dj < 3; dj++)
            xv[di * 3 + dj] = xT[((i + di) * 16 + (j + dj)) * 1024 + b];
    float accv[16];
#pragma unroll
    for (int o = 0; o < 16; o++) {
        float acc = bS[o];
#pragma unroll
        for (int k = 0; k < 9; k++) acc += wS[o * 9 + k] * xv[k];
        accv[o] = acc;
    }
    f16x8 lo, hi;
#pragma unroll
    for (int e = 0; e < 8; e++) { lo[e] = (_Float16)accv[e]; hi[e] = (_Float16)accv[8 + e]; }
    _Float16* dst = act1h + ((size_t)(p * 1024 + b)) * 16;
    *(f16x8*)dst = lo;
    *(f16x8*)(dst + 8) = hi;
    // ---- block-level stat reduction (s rows 0..15, q rows 16..31) ----
#pragma unroll
    for (int o = 0; o < 16; o++) {
        red[tid * 33 + o] = accv[o];
        red[tid * 33 + 16 + o] = accv[o] * accv[o];
    }
    __syncthreads();
    {
        int w = tid >> 6, lane = tid & 63, v = lane & 31, h = lane >> 5;
        int rbase = w * 64 + h * 32;
        float ssum = 0.f;
#pragma unroll
        for (int k = 0; k < 32; k++) ssum += red[(rbase + k) * 33 + v];
        ssum += __shfl_down(ssum, 32);
        if (h == 0) pp[w * 33 + v] = ssum;
    }
    __syncthreads();
    if (tid < 32) {
        float t4 = pp[tid] + pp[33 + tid] + pp[66 + tid] + pp[99 + tid];
        atomicAdd(acc1 + tid, t4);
    }
}

// ---------------- LC2 MFMA: act1h (+BN1/ReLU on read) -> act2h RAW; stats -> atomicAdd acc2 ----------------
// grid: 576 blocks 1-D, XCD swizzle (576 = 8*72). Wave: o32 x b64 (nt=4).
// W2h p-slice (10.2 KB) staged in LDS once per block, shared by all 4 waves (was 4x global re-fetch).
__global__ __launch_bounds__(256) void k_lc2m(const _Float16* __restrict__ act1h,
                                              const _Float16* __restrict__ W2h,
                                              const float* __restrict__ b2,
                                              const float* __restrict__ acc1,  // s[16] q[16]
                                              const float* __restrict__ g1,
                                              const float* __restrict__ be1,
                                              _Float16* __restrict__ act2h,
                                              float* __restrict__ acc2) {      // s[32] q[32]
    int bid = blockIdx.x;
    int wg = (bid & 7) * 72 + (bid >> 3);
    int p = wg >> 2, i = p / 12, j = p % 12;
    int tid = threadIdx.x, wv = tid >> 6, lane = tid & 63, n = lane & 15, quad = lane >> 4;
    int bbase = (wg & 3) * 256 + wv * 64;
    __shared__ _Float16 wL[10 * 512];      // 10240 B
    for (int idx = tid; idx < 640; idx += 256)
        *(f16x8*)(wL + idx * 8) = *(const f16x8*)(W2h + (size_t)p * 5120 + idx * 8);
    const float invN1 = 1.f / (1024.f * 196.f);
    f16x8 a8, c8;
#pragma unroll
    for (int e = 0; e < 8; e++) {
        int ch = (quad & 1) * 8 + e;
        float s = acc1[ch], q = acc1[16 + ch];
        float m = s * invN1, var = q * invN1 - m * m;
        float r = rsqrtf(var + EPS);
        float av = g1[ch] * r;
        a8[e] = (_Float16)av;
        c8[e] = (_Float16)(be1[ch] - m * av);
    }
    __syncthreads();
    f32x4 acc[2][4] = {};
#pragma unroll
    for (int t = 0; t < 5; t++) {
        int posA = 2 * t + (quad >> 1);         // 0..9 ; 9 hits wL zero plane
        int posB = posA > 8 ? 8 : posA;         // B reads pos8 (A slot is zero)
        int ip = (i + posB / 3) * 14 + (j + posB % 3);
        f16x8 afr[2];
#pragma unroll
        for (int ot = 0; ot < 2; ot++)
            afr[ot] = *(const f16x8*)(wL + posA * 512 + (ot * 16 + n) * 16 + (quad & 1) * 8);
#pragma unroll
        for (int nt = 0; nt < 4; nt++) {
            f16x8 xv = *(const f16x8*)(act1h + ((size_t)(ip * 1024 + bbase + nt * 16 + n)) * 16 + (quad & 1) * 8);
#pragma unroll
            for (int e = 0; e < 8; e++) {
                _Float16 v = xv[e] * a8[e] + c8[e];
                xv[e] = v > (_Float16)0.f ? v : (_Float16)0.f;
            }
#pragma unroll
            for (int ot = 0; ot < 2; ot++)
                acc[ot][nt] = __builtin_amdgcn_mfma_f32_16x16x32_f16(afr[ot], xv, acc[ot][nt], 0, 0, 0);
        }
    }
    float s_[8] = {}, q_[8] = {};
#pragma unroll
    for (int ot = 0; ot < 2; ot++) {
        float bias[4];
#pragma unroll
        for (int r = 0; r < 4; r++) bias[r] = b2[(ot * 16 + quad * 4 + r) * 144 + p];
#pragma unroll
        for (int nt = 0; nt < 4; nt++) {
            int b = bbase + nt * 16 + n;
            f16x4 st;
#pragma unroll
            for (int r = 0; r < 4; r++) {
                float v = acc[ot][nt][r] + bias[r];
                st[r] = (_Float16)v;
                s_[ot * 4 + r] += v; q_[ot * 4 + r] += v * v;
            }
            *(f16x4*)(act2h + ((size_t)(p * 1024 + b)) * 32 + ot * 16 + quad * 4) = st;
        }
    }
    __shared__ float red[64 * 65];
#pragma unroll
    for (int u = 0; u < 8; u++) {
        int o = (u >> 2) * 16 + quad * 4 + (u & 3);
        red[(2 * o) * 65 + wv * 16 + n] = s_[u];
        red[(2 * o + 1) * 65 + wv * 16 + n] = q_[u];
    }
    __syncthreads();
    if (tid < 64) {
        const float* row = red + tid * 65;
        float t0 = 0.f;
#pragma unroll
        for (int c = 0; c < 64; c++) t0 += row[c];
        atomicAdd(acc2 + (tid & 1) * 32 + (tid >> 1), t0);
    }
}

// ---------------- LC3 MFMA: act2h (+BN2/ReLU on read) -> act3h RAW; stats -> atomicAdd acc3 ----------------
// grid: 400 blocks 1-D, XCD swizzle (400 = 8*50). Wave: o64 x b64 (nt=4).
// W3h p-slice (36.9 KB) staged in LDS once per block, shared by all 4 waves (was 4x global re-fetch).
__global__ __launch_bounds__(256) void k_lc3m(const _Float16* __restrict__ act2h,
                                              const _Float16* __restrict__ W3h,
                                              const float* __restrict__ b3,
                                              const float* __restrict__ acc2,  // s[32] q[32]
                                              const float* __restrict__ g2,
                                              const float* __restrict__ be2,
                                              _Float16* __restrict__ act3h,
                                              float* __restrict__ acc3) {      // s[64] q[64]
    int bid = blockIdx.x;
    int wg = (bid & 7) * 50 + (bid >> 3);
    int p = wg >> 2, i = p / 10, j = p % 10;
    int tid = threadIdx.x, wv = tid >> 6, lane = tid & 63, n = lane & 15, quad = lane >> 4;
    int bbase = (wg & 3) * 256 + wv * 64;
    __shared__ _Float16 wL[9 * 2048];      // 36864 B
    for (int idx = tid; idx < 2304; idx += 256)
        *(f16x8*)(wL + idx * 8) = *(const f16x8*)(W3h + (size_t)p * 18432 + idx * 8);
    const float invN2 = 1.f / (1024.f * 144.f);
    f16x8 a8, c8;
#pragma unroll
    for (int e = 0; e < 8; e++) {
        int ch = quad * 8 + e;
        float s = acc2[ch], q = acc2[32 + ch];
        float m = s * invN2, var = q * invN2 - m * m;
        float r = rsqrtf(var + EPS);
        float av = g2[ch] * r;
        a8[e] = (_Float16)av;
        c8[e] = (_Float16)(be2[ch] - m * av);
    }
    __syncthreads();
    f32x4 acc[4][4] = {};
#pragma unroll
    for (int pos = 0; pos < 9; pos++) {
        int ip = (i + pos / 3) * 12 + (j + pos % 3);
        f16x8 afr[4];
#pragma unroll
        for (int ot = 0; ot < 4; ot++)
            afr[ot] = *(const f16x8*)(wL + pos * 2048 + (ot * 16 + n) * 32 + quad * 8);
#pragma unroll
        for (int nt = 0; nt < 4; nt++) {
            f16x8 xv = *(const f16x8*)(act2h + ((size_t)(ip * 1024 + bbase + nt * 16 + n)) * 32 + quad * 8);
#pragma unroll
            for (int e = 0; e < 8; e++) {
                _Float16 v = xv[e] * a8[e] + c8[e];
                xv[e] = v > (_Float16)0.f ? v : (_Float16)0.f;
            }
#pragma unroll
            for (int ot = 0; ot < 4; ot++)
                acc[ot][nt] = __builtin_amdgcn_mfma_f32_16x16x32_f16(afr[ot], xv, acc[ot][nt], 0, 0, 0);
        }
    }
    float s_[16] = {}, q_[16] = {};
#pragma unroll
    for (int ot = 0; ot < 4; ot++) {
        float bias[4];
#pragma unroll
        for (int r = 0; r < 4; r++) bias[r] = b3[(ot * 16 + quad * 4 + r) * 100 + p];
#pragma unroll
        for (int nt = 0; nt < 4; nt++) {
            int b = bbase + nt * 16 + n;
            f16x4 st;
#pragma unroll
            for (int r = 0; r < 4; r++) {
                float v = acc[ot][nt][r] + bias[r];
                st[r] = (_Float16)v;
                s_[ot * 4 + r] += v; q_[ot * 4 + r] += v * v;
            }
            *(f16x4*)(act3h + ((size_t)(p * 1024 + b)) * 64 + ot * 16 + quad * 4) = st;
        }
    }
    __shared__ float red[128 * 65];
#pragma unroll
    for (int u = 0; u < 16; u++) {
        int o = (u >> 2) * 16 + quad * 4 + (u & 3);
        red[(2 * o) * 65 + wv * 16 + n] = s_[u];
        red[(2 * o + 1) * 65 + wv * 16 + n] = q_[u];
    }
    __syncthreads();
    if (tid < 128) {
        const float* row = red + tid * 65;
        float t0 = 0.f;
#pragma unroll
        for (int c = 0; c < 64; c++) t0 += row[c];
        atomicAdd(acc3 + (tid & 1) * 64 + (tid >> 1), t0);
    }
}

// ---------------- FC: tanh(BN3(act3h)) @ fcW^T -> partials [p][jj][b] ----------------
__global__ __launch_bounds__(256) void k_fc(const _Float16* __restrict__ act3h,
                                            const float* __restrict__ fcW,
                                            const float* __restrict__ acc3,  // s[64] q[64]
                                            const float* __restrict__ g3,
                                            const float* __restrict__ be3,
                                            float* __restrict__ fpart) {
    int p = blockIdx.y;
    int tid = threadIdx.x;
    int b = blockIdx.x * 256 + tid;
    __shared__ float wS[640], aS[64], cS[64];
    for (int idx = tid; idx < 640; idx += 256) {
        int o = idx / 10, jj = idx % 10;
        wS[idx] = fcW[jj * 6400 + o * 100 + p];
    }
    if (tid < 64) {
        const float invN3 = 1.f / (1024.f * 100.f);
        float s = acc3[tid], q = acc3[64 + tid];
        float m = s * invN3, var = q * invN3 - m * m;
        float r = rsqrtf(var + EPS);
        float av = g3[tid] * r;
        aS[tid] = av; cS[tid] = be3[tid] - m * av;
    }
    __syncthreads();
    float acc[10];
#pragma unroll
    for (int jj = 0; jj < 10; jj++) acc[jj] = 0.f;
    const _Float16* src = act3h + ((size_t)(p * 1024 + b)) * 64;
    for (int o8 = 0; o8 < 8; o8++) {
        f16x8 xv = *(const f16x8*)(src + o8 * 8);
#pragma unroll
        for (int e = 0; e < 8; e++) {
            int o = o8 * 8 + e;
            float v = fmaf(aS[o], (float)xv[e], cS[o]);
            float e2 = __expf(2.f * v);
            v = 1.f - 2.f / (e2 + 1.f);   // tanh, safe at +/-inf
#pragma unroll
            for (int jj = 0; jj < 10; jj++) acc[jj] = fmaf(wS[o * 10 + jj], v, acc[jj]);
        }
    }
#pragma unroll
    for (int jj = 0; jj < 10; jj++) fpart[((size_t)p * 10 + jj) * 1024 + b] = acc[jj];
}

// ---------------- reduce fc partials + bias -> out ----------------
__global__ __launch_bounds__(256) void k_fc_reduce(const float* __restrict__ fpart,
                                                   const float* __restrict__ fcb,
                                                   float* __restrict__ out) {
    int idx = blockIdx.x * 256 + threadIdx.x;  // jj*1024 + b
    int jj = idx >> 10, b = idx & 1023;
    float acc = fcb[jj];
    for (int p = 0; p < 100; p++) acc += fpart[(p * 10 + jj) * 1024 + b];
    out[b * 10 + jj] = acc;
}

extern "C" void kernel_launch(void* const* d_in, const int* in_sizes, int n_in,
                              void* d_out, int out_size, void* d_ws, size_t ws_size,
                              hipStream_t stream) {
    const float* x   = (const float*)d_in[0];
    const float* W1  = (const float*)d_in[1];
    const float* b1  = (const float*)d_in[2];
    const float* g1  = (const float*)d_in[3];
    const float* be1 = (const float*)d_in[4];
    const float* W2  = (const float*)d_in[5];
    const float* b2  = (const float*)d_in[6];
    const float* g2  = (const float*)d_in[7];
    const float* be2 = (const float*)d_in[8];
    const float* W3  = (const float*)d_in[9];
    const float* b3  = (const float*)d_in[10];
    const float* g3  = (const float*)d_in[11];
    const float* be3 = (const float*)d_in[12];
    const float* fcW = (const float*)d_in[13];
    const float* fcb = (const float*)d_in[14];
    float* out = (float*)d_out;
    float* ws = (float*)d_ws;

    float* xT    = ws + XT_OFF;
    _Float16* act1h = (_Float16*)(ws + ACT1_OFF);
    _Float16* act2h = (_Float16*)(ws + ACT2_OFF);
    _Float16* act3h = (_Float16*)(ws + ACT3_OFF);
    _Float16* W2h   = (_Float16*)(ws + W2H_OFF);
    _Float16* W3h   = (_Float16*)(ws + W3H_OFF);
    float* fp   = ws + FP_OFF;
    float* acc  = ws + ACC_OFF;

    k_prep<<<3572, 256, 0, stream>>>(W2, W3, x, W2h, W3h, xT, acc);
    k_lc1<<<784, 256, 0, stream>>>(xT, W1, b1, act1h, acc);
    k_lc2m<<<576, 256, 0, stream>>>(act1h, W2h, b2, acc, g1, be1, act2h, acc + 32);
    k_lc3m<<<400, 256, 0, stream>>>(act2h, W3h, b3, acc + 32, g2, be2, act3h, acc + 96);
    k_fc<<<dim3(4, 100), 256, 0, stream>>>(act3h, fcW, acc + 96, g3, be3, fp);
    k_fc_reduce<<<40, 256, 0, stream>>>(fp, fcb, out);
}

// Round 7
// 144.995 us; speedup vs baseline: 1.2132x; 1.1055x over previous
//
#include <hip/hip_runtime.h>

#define EPS 1e-5f

typedef _Float16 f16x8 __attribute__((ext_vector_type(8)));
typedef _Float16 f16x4 __attribute__((ext_vector_type(4)));
typedef float f32x4 __attribute__((ext_vector_type(4)));

// ---- workspace layout (float offsets) ----
#define XT_OFF    0u          // 256*1024 fp32
#define ACT1_OFF  262144u     // f16 196*1024*16
#define ACT2_OFF  1867776u    // f16 144*1024*32
#define ACT3_OFF  4227072u    // f16 100*1024*64
#define W2H_OFF   7503872u    // f16 144*10*512 = 737,280 halves  [p][pos10][o32][c16], pos9 zero
#define W3H_OFF   7872512u    // f16 900*2048  = 1,843,200 halves [p*9+pos][o64][c32]
#define FP_OFF    9598976u    // fp32 100*10*1024
#define ACC_OFF   10622976u   // fp32 8 reps x 256: per rep: s1[0,16) q1[16,32) s2[32,64) q2[64,96) s3[96,160) q3[160,224)
// Replicated 8-way (rep = bid&7, 1KB stride) to cut per-address atomic chains 8x
// (atomic serialization at home-L2 was the surviving theory for R5's +16us).

// ---------------- prep: coalesced LDS-tiled transposes + acc zero ----------------
__global__ __launch_bounds__(256) void k_prep(const float* __restrict__ W2,
                                              const float* __restrict__ W3,
                                              const float* __restrict__ x,
                                              _Float16* __restrict__ W2h,
                                              _Float16* __restrict__ W3h,
                                              float* __restrict__ xT,
                                              float* __restrict__ acc) {
    int gb = blockIdx.x, tid = threadIdx.x;
    __shared__ float tile[32][33];
    int tx = tid & 31, ty = tid >> 5;                 // 32 x 8
    if (gb < 656) {
        // ---- W2 transpose: tiles 16 (rows) x 41 (cols) ----
        int tR = gb / 41, tC = gb % 41;
        int oc0 = tR * 32, pp0 = tC * 32;
#pragma unroll
        for (int r = 0; r < 4; r++) {
            int col = pp0 + tx;
            if (col < 1296) tile[ty + 8 * r][tx] = W2[(size_t)(oc0 + ty + 8 * r) * 1296 + col];
        }
        __syncthreads();
#pragma unroll
        for (int r = 0; r < 4; r++) {
            int pr = pp0 + ty + 8 * r;
            if (pr < 1296) {
                int p = pr / 9, pos = pr - 9 * p;
                W2h[(size_t)(p * 10 + pos) * 512 + oc0 + tx] = (_Float16)tile[tx][ty + 8 * r];
            }
        }
        return;
    }
    if (gb < 692) {
        // ---- zero plane pos=9 of W2h (144*512 halves) + zero replicated acc ----
        if (gb == 656) {
#pragma unroll
            for (int r = 0; r < 8; r++) acc[r * 256 + tid] = 0.f;
        }
        int idx = (gb - 656) * 256 + tid;             // 0..9215
        int p = idx >> 6, ocv = idx & 63;
        f16x8 z = {(_Float16)0.f, (_Float16)0.f, (_Float16)0.f, (_Float16)0.f,
                   (_Float16)0.f, (_Float16)0.f, (_Float16)0.f, (_Float16)0.f};
        *(f16x8*)(W2h + (size_t)(p * 10 + 9) * 512 + ocv * 8) = z;
        return;
    }
    if (gb < 2548) {
        // ---- W3 transpose: tiles 64 (rows) x 29 (cols) ----
        int t = gb - 692;
        int tR = t / 29, tC = t % 29;
        int oc0 = tR * 32, pp0 = tC * 32;
#pragma unroll
        for (int r = 0; r < 4; r++) {
            int col = pp0 + tx;
            if (col < 900) tile[ty + 8 * r][tx] = W3[(size_t)(oc0 + ty + 8 * r) * 900 + col];
        }
        __syncthreads();
#pragma unroll
        for (int r = 0; r < 4; r++) {
            int pr = pp0 + ty + 8 * r;
            if (pr < 900) W3h[(size_t)pr * 2048 + oc0 + tx] = (_Float16)tile[tx][ty + 8 * r];
        }
        return;
    }
    {
        // ---- x transpose: 1024 tiles of 16x16 ----
        int t = gb - 2548;
        float* t17 = &tile[0][0];                     // use as [16][17]
        int tx4 = tid & 15, ty4 = tid >> 4;
        int p0 = (t & 15) * 16, b0 = (t >> 4) * 16;
        t17[ty4 * 17 + tx4] = x[(b0 + ty4) * 256 + p0 + tx4];
        __syncthreads();
        xT[(p0 + ty4) * 1024 + b0 + tx4] = t17[tx4 * 17 + ty4];
    }
}

// ---------------- LC1 (fp32 math): xT -> act1h f16 [p][b][c16] RAW; block stats -> atomicAdd acc rep ----------------
// grid: 784 blocks 1-D, XCD-contiguous swizzle (784 = 8*98)
__global__ __launch_bounds__(256) void k_lc1(const float* __restrict__ xT,
                                             const float* __restrict__ W1,
                                             const float* __restrict__ b1,
                                             _Float16* __restrict__ act1h,
                                             float* __restrict__ acc) {
    int bid = blockIdx.x;
    int rep = bid & 7;
    int wg = (bid & 7) * 98 + (bid >> 3);   // XCD j owns wg in [j*98, (j+1)*98)
    int p = wg >> 2;                        // 0..195, contiguous per XCD
    int i = p / 14, j = p % 14;
    int tid = threadIdx.x;
    int b = (wg & 3) * 256 + tid;
    __shared__ float wS[144], bS[16];
    __shared__ float red[256 * 33];  // [thread][32 vals], pad 33 -> conflict-free
    __shared__ float pp[4 * 33];
    if (tid < 144) { int o = tid / 9, k = tid % 9; wS[tid] = W1[(o * 196 + p) * 9 + k]; }
    if (tid < 16) bS[tid] = b1[tid * 196 + p];
    __syncthreads();
    float xv[9];
#pragma unroll
    for (int di = 0; di < 3; di++)
#pragma unroll
        for (int dj = 0; dj < 3; dj++)
            xv[di * 3 + dj] = xT[((i + di) * 16 + (j + dj)) * 1024 + b];
    float accv[16];
#pragma unroll
    for (int o = 0; o < 16; o++) {
        float acc2_ = bS[o];
#pragma unroll
        for (int k = 0; k < 9; k++) acc2_ += wS[o * 9 + k] * xv[k];
        accv[o] = acc2_;
    }
    f16x8 lo, hi;
#pragma unroll
    for (int e = 0; e < 8; e++) { lo[e] = (_Float16)accv[e]; hi[e] = (_Float16)accv[8 + e]; }
    _Float16* dst = act1h + ((size_t)(p * 1024 + b)) * 16;
    *(f16x8*)dst = lo;
    *(f16x8*)(dst + 8) = hi;
    // ---- block-level stat reduction (s rows 0..15, q rows 16..31) ----
#pragma unroll
    for (int o = 0; o < 16; o++) {
        red[tid * 33 + o] = accv[o];
        red[tid * 33 + 16 + o] = accv[o] * accv[o];
    }
    __syncthreads();
    {
        int w = tid >> 6, lane = tid & 63, v = lane & 31, h = lane >> 5;
        int rbase = w * 64 + h * 32;
        float ssum = 0.f;
#pragma unroll
        for (int k = 0; k < 32; k++) ssum += red[(rbase + k) * 33 + v];
        ssum += __shfl_down(ssum, 32);
        if (h == 0) pp[w * 33 + v] = ssum;
    }
    __syncthreads();
    if (tid < 32) {
        float t4 = pp[tid] + pp[33 + tid] + pp[66 + tid] + pp[99 + tid];
        atomicAdd(acc + rep * 256 + tid, t4);
    }
}

// ---------------- LC2 MFMA: act1h (+BN1/ReLU on read) -> act2h RAW; stats -> atomicAdd acc rep ----------------
// grid: 576 blocks 1-D, XCD swizzle (576 = 8*72). Wave: o32 x b64 (nt=4). W2h p-slice staged in LDS.
__global__ __launch_bounds__(256) void k_lc2m(const _Float16* __restrict__ act1h,
                                              const _Float16* __restrict__ W2h,
                                              const float* __restrict__ b2,
                                              const float* __restrict__ acc,
                                              const float* __restrict__ g1,
                                              const float* __restrict__ be1,
                                              _Float16* __restrict__ act2h,
                                              float* __restrict__ accw) {
    int bid = blockIdx.x;
    int rep = bid & 7;
    int wg = (bid & 7) * 72 + (bid >> 3);
    int p = wg >> 2, i = p / 12, j = p % 12;
    int tid = threadIdx.x, wv = tid >> 6, lane = tid & 63, n = lane & 15, quad = lane >> 4;
    int bbase = (wg & 3) * 256 + wv * 64;
    __shared__ _Float16 wL[10 * 512];      // 10240 B
    for (int idx = tid; idx < 640; idx += 256)
        *(f16x8*)(wL + idx * 8) = *(const f16x8*)(W2h + (size_t)p * 5120 + idx * 8);
    const float invN1 = 1.f / (1024.f * 196.f);
    f16x8 a8, c8;
#pragma unroll
    for (int e = 0; e < 8; e++) {
        int ch = (quad & 1) * 8 + e;
        float s = 0.f, q = 0.f;
#pragma unroll
        for (int r = 0; r < 8; r++) { s += acc[r * 256 + ch]; q += acc[r * 256 + 16 + ch]; }
        float m = s * invN1, var = q * invN1 - m * m;
        float rr = rsqrtf(var + EPS);
        float av = g1[ch] * rr;
        a8[e] = (_Float16)av;
        c8[e] = (_Float16)(be1[ch] - m * av);
    }
    __syncthreads();
    f32x4 accm[2][4] = {};
#pragma unroll
    for (int t = 0; t < 5; t++) {
        int posA = 2 * t + (quad >> 1);         // 0..9 ; 9 hits wL zero plane
        int posB = posA > 8 ? 8 : posA;         // B reads pos8 (A slot is zero)
        int ip = (i + posB / 3) * 14 + (j + posB % 3);
        f16x8 afr[2];
#pragma unroll
        for (int ot = 0; ot < 2; ot++)
            afr[ot] = *(const f16x8*)(wL + posA * 512 + (ot * 16 + n) * 16 + (quad & 1) * 8);
#pragma unroll
        for (int nt = 0; nt < 4; nt++) {
            f16x8 xv = *(const f16x8*)(act1h + ((size_t)(ip * 1024 + bbase + nt * 16 + n)) * 16 + (quad & 1) * 8);
#pragma unroll
            for (int e = 0; e < 8; e++) {
                _Float16 v = xv[e] * a8[e] + c8[e];
                xv[e] = v > (_Float16)0.f ? v : (_Float16)0.f;
            }
#pragma unroll
            for (int ot = 0; ot < 2; ot++)
                accm[ot][nt] = __builtin_amdgcn_mfma_f32_16x16x32_f16(afr[ot], xv, accm[ot][nt], 0, 0, 0);
        }
    }
    float s_[8] = {}, q_[8] = {};
#pragma unroll
    for (int ot = 0; ot < 2; ot++) {
        float bias[4];
#pragma unroll
        for (int r = 0; r < 4; r++) bias[r] = b2[(ot * 16 + quad * 4 + r) * 144 + p];
#pragma unroll
        for (int nt = 0; nt < 4; nt++) {
            int b = bbase + nt * 16 + n;
            f16x4 st;
#pragma unroll
            for (int r = 0; r < 4; r++) {
                float v = accm[ot][nt][r] + bias[r];
                st[r] = (_Float16)v;
                s_[ot * 4 + r] += v; q_[ot * 4 + r] += v * v;
            }
            *(f16x4*)(act2h + ((size_t)(p * 1024 + b)) * 32 + ot * 16 + quad * 4) = st;
        }
    }
    __shared__ float red[64 * 65];
#pragma unroll
    for (int u = 0; u < 8; u++) {
        int o = (u >> 2) * 16 + quad * 4 + (u & 3);
        red[(2 * o) * 65 + wv * 16 + n] = s_[u];
        red[(2 * o + 1) * 65 + wv * 16 + n] = q_[u];
    }
    __syncthreads();
    if (tid < 64) {
        const float* row = red + tid * 65;
        float t0 = 0.f;
#pragma unroll
        for (int c = 0; c < 64; c++) t0 += row[c];
        atomicAdd(accw + rep * 256 + 32 + (tid & 1) * 32 + (tid >> 1), t0);
    }
}

// ---------------- LC3 MFMA: act2h (+BN2/ReLU on read) -> act3h RAW; stats -> atomicAdd acc rep ----------------
// grid: 400 blocks 1-D, XCD swizzle (400 = 8*50). Wave: o64 x b64 (nt=4). W3h p-slice staged in LDS.
__global__ __launch_bounds__(256) void k_lc3m(const _Float16* __restrict__ act2h,
                                              const _Float16* __restrict__ W3h,
                                              const float* __restrict__ b3,
                                              const float* __restrict__ acc,
                                              const float* __restrict__ g2,
                                              const float* __restrict__ be2,
                                              _Float16* __restrict__ act3h,
                                              float* __restrict__ accw) {
    int bid = blockIdx.x;
    int rep = bid & 7;
    int wg = (bid & 7) * 50 + (bid >> 3);
    int p = wg >> 2, i = p / 10, j = p % 10;
    int tid = threadIdx.x, wv = tid >> 6, lane = tid & 63, n = lane & 15, quad = lane >> 4;
    int bbase = (wg & 3) * 256 + wv * 64;
    __shared__ _Float16 wL[9 * 2048];      // 36864 B
    for (int idx = tid; idx < 2304; idx += 256)
        *(f16x8*)(wL + idx * 8) = *(const f16x8*)(W3h + (size_t)p * 18432 + idx * 8);
    const float invN2 = 1.f / (1024.f * 144.f);
    f16x8 a8, c8;
#pragma unroll
    for (int e = 0; e < 8; e++) {
        int ch = quad * 8 + e;
        float s = 0.f, q = 0.f;
#pragma unroll
        for (int r = 0; r < 8; r++) { s += acc[r * 256 + 32 + ch]; q += acc[r * 256 + 64 + ch]; }
        float m = s * invN2, var = q * invN2 - m * m;
        float rr = rsqrtf(var + EPS);
        float av = g2[ch] * rr;
        a8[e] = (_Float16)av;
        c8[e] = (_Float16)(be2[ch] - m * av);
    }
    __syncthreads();
    f32x4 accm[4][4] = {};
#pragma unroll
    for (int pos = 0; pos < 9; pos++) {
        int ip = (i + pos / 3) * 12 + (j + pos % 3);
        f16x8 afr[4];
#pragma unroll
        for (int ot = 0; ot < 4; ot++)
            afr[ot] = *(const f16x8*)(wL + pos * 2048 + (ot * 16 + n) * 32 + quad * 8);
#pragma unroll
        for (int nt = 0; nt < 4; nt++) {
            f16x8 xv = *(const f16x8*)(act2h + ((size_t)(ip * 1024 + bbase + nt * 16 + n)) * 32 + quad * 8);
#pragma unroll
            for (int e = 0; e < 8; e++) {
                _Float16 v = xv[e] * a8[e] + c8[e];
                xv[e] = v > (_Float16)0.f ? v : (_Float16)0.f;
            }
#pragma unroll
            for (int ot = 0; ot < 4; ot++)
                accm[ot][nt] = __builtin_amdgcn_mfma_f32_16x16x32_f16(afr[ot], xv, accm[ot][nt], 0, 0, 0);
        }
    }
    float s_[16] = {}, q_[16] = {};
#pragma unroll
    for (int ot = 0; ot < 4; ot++) {
        float bias[4];
#pragma unroll
        for (int r = 0; r < 4; r++) bias[r] = b3[(ot * 16 + quad * 4 + r) * 100 + p];
#pragma unroll
        for (int nt = 0; nt < 4; nt++) {
            int b = bbase + nt * 16 + n;
            f16x4 st;
#pragma unroll
            for (int r = 0; r < 4; r++) {
                float v = accm[ot][nt][r] + bias[r];
                st[r] = (_Float16)v;
                s_[ot * 4 + r] += v; q_[ot * 4 + r] += v * v;
            }
            *(f16x4*)(act3h + ((size_t)(p * 1024 + b)) * 64 + ot * 16 + quad * 4) = st;
        }
    }
    __shared__ float red[128 * 65];
#pragma unroll
    for (int u = 0; u < 16; u++) {
        int o = (u >> 2) * 16 + quad * 4 + (u & 3);
        red[(2 * o) * 65 + wv * 16 + n] = s_[u];
        red[(2 * o + 1) * 65 + wv * 16 + n] = q_[u];
    }
    __syncthreads();
    if (tid < 128) {
        const float* row = red + tid * 65;
        float t0 = 0.f;
#pragma unroll
        for (int c = 0; c < 64; c++) t0 += row[c];
        atomicAdd(accw + rep * 256 + 96 + (tid & 1) * 64 + (tid >> 1), t0);
    }
}

// ---------------- FC: tanh(BN3(act3h)) @ fcW^T -> partials [p][jj][b] ----------------
__global__ __launch_bounds__(256) void k_fc(const _Float16* __restrict__ act3h,
                                            const float* __restrict__ fcW,
                                            const float* __restrict__ acc,
                                            const float* __restrict__ g3,
                                            const float* __restrict__ be3,
                                            float* __restrict__ fpart) {
    int p = blockIdx.y;
    int tid = threadIdx.x;
    int b = blockIdx.x * 256 + tid;
    __shared__ float wS[640], aS[64], cS[64];
    for (int idx = tid; idx < 640; idx += 256) {
        int o = idx / 10, jj = idx % 10;
        wS[idx] = fcW[jj * 6400 + o * 100 + p];
    }
    if (tid < 64) {
        const float invN3 = 1.f / (1024.f * 100.f);
        float s = 0.f, q = 0.f;
#pragma unroll
        for (int r = 0; r < 8; r++) { s += acc[r * 256 + 96 + tid]; q += acc[r * 256 + 160 + tid]; }
        float m = s * invN3, var = q * invN3 - m * m;
        float rr = rsqrtf(var + EPS);
        float av = g3[tid] * rr;
        aS[tid] = av; cS[tid] = be3[tid] - m * av;
    }
    __syncthreads();
    float accv[10];
#pragma unroll
    for (int jj = 0; jj < 10; jj++) accv[jj] = 0.f;
    const _Float16* src = act3h + ((size_t)(p * 1024 + b)) * 64;
    for (int o8 = 0; o8 < 8; o8++) {
        f16x8 xv = *(const f16x8*)(src + o8 * 8);
#pragma unroll
        for (int e = 0; e < 8; e++) {
            int o = o8 * 8 + e;
            float v = fmaf(aS[o], (float)xv[e], cS[o]);
            float e2 = __expf(2.f * v);
            v = 1.f - 2.f / (e2 + 1.f);   // tanh, safe at +/-inf
#pragma unroll
            for (int jj = 0; jj < 10; jj++) accv[jj] = fmaf(wS[o * 10 + jj], v, accv[jj]);
        }
    }
#pragma unroll
    for (int jj = 0; jj < 10; jj++) fpart[((size_t)p * 10 + jj) * 1024 + b] = accv[jj];
}

// ---------------- reduce fc partials + bias -> out ----------------
__global__ __launch_bounds__(256) void k_fc_reduce(const float* __restrict__ fpart,
                                                   const float* __restrict__ fcb,
                                                   float* __restrict__ out) {
    int idx = blockIdx.x * 256 + threadIdx.x;  // jj*1024 + b
    int jj = idx >> 10, b = idx & 1023;
    float acc = fcb[jj];
    for (int p = 0; p < 100; p++) acc += fpart[(p * 10 + jj) * 1024 + b];
    out[b * 10 + jj] = acc;
}

extern "C" void kernel_launch(void* const* d_in, const int* in_sizes, int n_in,
                              void* d_out, int out_size, void* d_ws, size_t ws_size,
                              hipStream_t stream) {
    const float* x   = (const float*)d_in[0];
    const float* W1  = (const float*)d_in[1];
    const float* b1  = (const float*)d_in[2];
    const float* g1  = (const float*)d_in[3];
    const float* be1 = (const float*)d_in[4];
    const float* W2  = (const float*)d_in[5];
    const float* b2  = (const float*)d_in[6];
    const float* g2  = (const float*)d_in[7];
    const float* be2 = (const float*)d_in[8];
    const float* W3  = (const float*)d_in[9];
    const float* b3  = (const float*)d_in[10];
    const float* g3  = (const float*)d_in[11];
    const float* be3 = (const float*)d_in[12];
    const float* fcW = (const float*)d_in[13];
    const float* fcb = (const float*)d_in[14];
    float* out = (float*)d_out;
    float* ws = (float*)d_ws;

    float* xT    = ws + XT_OFF;
    _Float16* act1h = (_Float16*)(ws + ACT1_OFF);
    _Float16* act2h = (_Float16*)(ws + ACT2_OFF);
    _Float16* act3h = (_Float16*)(ws + ACT3_OFF);
    _Float16* W2h   = (_Float16*)(ws + W2H_OFF);
    _Float16* W3h   = (_Float16*)(ws + W3H_OFF);
    float* fp   = ws + FP_OFF;
    float* acc  = ws + ACC_OFF;

    k_prep<<<3572, 256, 0, stream>>>(W2, W3, x, W2h, W3h, xT, acc);
    k_lc1<<<784, 256, 0, stream>>>(xT, W1, b1, act1h, acc);
    k_lc2m<<<576, 256, 0, stream>>>(act1h, W2h, b2, acc, g1, be1, act2h, acc);
    k_lc3m<<<400, 256, 0, stream>>>(act2h, W3h, b3, acc, g2, be2, act3h, acc);
    k_fc<<<dim3(4, 100), 256, 0, stream>>>(act3h, fcW, acc, g3, be3, fp);
    k_fc_reduce<<<40, 256, 0, stream>>>(fp, fcb, out);
}